// Round 1
// baseline (204.095 us; speedup 1.0000x reference)
//
#include <hip/hip_runtime.h>

// ---------------------------------------------------------------------------
// DeepFM forward, MI355X.
// Pipeline:
//   1) transpose W1,W2 -> bf16 N-major (W^T) for NT MFMA GEMM
//   2) embed kernel: gathers, fm_first+fm_second (exact fp32), so -> bf16
//   3) GEMM1: Z1 = so @ W1          (bf16 MFMA, fp32 out; b1 cancels in BN)
//   4) column stats Z1 (deterministic 2-pass), fold BN -> a1,c1
//   5) BN apply: D1 = bf16(Z1*a1 + c1)
//   6) GEMM2: Z2 = D1 @ W2          (b2 cancels in BN)
//   7) column stats Z2 -> a2,c2
//   8) final: out[b] = partial[b] + sum_c(Z2[b,c]*a2[c] + c2[c])
// ---------------------------------------------------------------------------

#define B_ROWS 16384
#define NF 40
#define NDNS 13
#define NSP 27
#define EDIM 16
#define VOCAB 100000
#define D0 640
#define H1 512
#define H2 256
#define EPSV 1e-5f

typedef short bf16x8 __attribute__((ext_vector_type(8)));
typedef float f32x4 __attribute__((ext_vector_type(4)));
typedef unsigned short u16;

__device__ inline u16 f2bf(float x) {
    unsigned u = __float_as_uint(x);
    unsigned r = (u + 0x7fffu + ((u >> 16) & 1u)) >> 16;   // RNE
    return (u16)r;
}

__device__ inline void async16(const void* g, void* l) {
    __builtin_amdgcn_global_load_lds(
        (const __attribute__((address_space(1))) void*)g,
        (__attribute__((address_space(3))) void*)l, 16, 0, 0);
}

// ---------------------------------------------------------------------------
// W (K x N f32) -> WT (N x K bf16)
__global__ __launch_bounds__(256) void transpose_bf16_k(
    const float* __restrict__ W, u16* __restrict__ WT, int K, int N)
{
    __shared__ float tile[32][33];
    int k0 = blockIdx.x * 32, n0 = blockIdx.y * 32;
    int tx = threadIdx.x & 31, ty4 = (threadIdx.x >> 5) * 4;
#pragma unroll
    for (int r = 0; r < 4; ++r)
        tile[ty4 + r][tx] = W[(size_t)(k0 + ty4 + r) * N + n0 + tx];
    __syncthreads();
#pragma unroll
    for (int r = 0; r < 4; ++r)
        WT[(size_t)(n0 + ty4 + r) * K + k0 + tx] = f2bf(tile[tx][ty4 + r]);
}

// ---------------------------------------------------------------------------
// Embedding + FM (exact fp32) + so -> bf16.
// 256 thr = 16 rows/block, 16 threads per row (one per e).
__global__ __launch_bounds__(256) void embed_k(
    const int* __restrict__ Xi, const float* __restrict__ Xv,
    const float* __restrict__ bias,
    const float* __restrict__ dw1, const float* __restrict__ db1,
    const float* __restrict__ e1,
    const float* __restrict__ dw2, const float* __restrict__ db2,
    const float* __restrict__ e2,
    u16* __restrict__ so_bf, float* __restrict__ partial)
{
    const int t = threadIdx.x;
    const int e = t & 15;
    const int b = blockIdx.x * 16 + (t >> 4);
    const int* xr = Xi + (size_t)b * NF;
    const float* xvr = Xv + (size_t)b * NF;

    float accf = 0.f, s1 = 0.f, sq = 0.f;
#pragma unroll
    for (int f = 0; f < NDNS; ++f) {
        float x = (float)xr[f];
        float xv = xvr[f];
        float fo = (x * dw1[f * 16 + e] + db1[f * 16 + e]) * xv;
        float so = (x * dw2[f * 16 + e] + db2[f * 16 + e]) * xv;
        accf += fo; s1 += so; sq += so * so;
        so_bf[(size_t)b * D0 + f * 16 + e] = f2bf(so);
    }
#pragma unroll 4
    for (int f = NDNS; f < NF; ++f) {
        int idx = xr[f];
        float xv = xvr[f];
        int s = f - NDNS;
        size_t off = (size_t)s * VOCAB * 16 + (size_t)idx * 16 + e;
        float fo = e1[off] * xv;
        float so = e2[off] * xv;
        accf += fo; s1 += so; sq += so * so;
        so_bf[(size_t)b * D0 + f * 16 + e] = f2bf(so);
    }
    float val = accf + 0.5f * (s1 * s1 - sq);
    val += __shfl_xor(val, 1);
    val += __shfl_xor(val, 2);
    val += __shfl_xor(val, 4);
    val += __shfl_xor(val, 8);
    if (e == 0) partial[b] = val + bias[b];
}

// ---------------------------------------------------------------------------
// NT GEMM: C[M,N] = A[M,K] * Bt[N,K]^T, bf16 in, f32 out.
// 128x128 tile, BK=64, 4 waves (each 64x64), mfma_f32_16x16x32_bf16.
__global__ __launch_bounds__(256) void gemm_nt(
    const u16* __restrict__ A, const u16* __restrict__ Bt,
    float* __restrict__ C, int M, int N, int K)
{
    __shared__ u16 As[128 * 64];
    __shared__ u16 Bs[128 * 64];
    const int tid = threadIdx.x;
    const int lane = tid & 63;
    const int w = tid >> 6;
    const int m0 = blockIdx.x * 128;
    const int n0 = blockIdx.y * 128;
    const int wr = w >> 1, wc = w & 1;

    const int srow = lane >> 3;          // 0..7
    const int scol = (lane & 7) * 8;     // bf16 elems

    f32x4 acc[4][4] = {};

    for (int kt = 0; kt < K; kt += 64) {
#pragma unroll
        for (int j = 0; j < 4; ++j) {
            int r0 = w * 32 + j * 8;
            const u16* gA = A + (size_t)(m0 + r0 + srow) * K + kt + scol;
            async16(gA, &As[r0 * 64]);
            const u16* gB = Bt + (size_t)(n0 + r0 + srow) * K + kt + scol;
            async16(gB, &Bs[r0 * 64]);
        }
        asm volatile("s_waitcnt vmcnt(0)" ::: "memory");
        __syncthreads();
#pragma unroll
        for (int kk = 0; kk < 2; ++kk) {
            bf16x8 af[4], bfr[4];
#pragma unroll
            for (int i = 0; i < 4; ++i) {
                int ar = wr * 64 + i * 16 + (lane & 15);
                af[i] = *(const bf16x8*)&As[ar * 64 + kk * 32 + (lane >> 4) * 8];
                int br = wc * 64 + i * 16 + (lane & 15);
                bfr[i] = *(const bf16x8*)&Bs[br * 64 + kk * 32 + (lane >> 4) * 8];
            }
#pragma unroll
            for (int i = 0; i < 4; ++i)
#pragma unroll
                for (int j2 = 0; j2 < 4; ++j2)
                    acc[i][j2] = __builtin_amdgcn_mfma_f32_16x16x32_bf16(
                        af[i], bfr[j2], acc[i][j2], 0, 0, 0);
        }
        __syncthreads();
    }
    // C/D layout (m89): col = lane&15, row = (lane>>4)*4 + reg
#pragma unroll
    for (int i = 0; i < 4; ++i)
#pragma unroll
        for (int j2 = 0; j2 < 4; ++j2) {
            int row = m0 + wr * 64 + i * 16 + (lane >> 4) * 4;
            int col = n0 + wc * 64 + j2 * 16 + (lane & 15);
#pragma unroll
            for (int q = 0; q < 4; ++q)
                C[(size_t)(row + q) * N + col] = acc[i][j2][q];
        }
}

// ---------------------------------------------------------------------------
// Column partial sums/sumsq. grid = (N/256, chunks), block 256.
__global__ __launch_bounds__(256) void colstats_k(
    const float* __restrict__ Z, float* __restrict__ psum,
    float* __restrict__ psq, int N, int rpc)
{
    int col = blockIdx.x * 256 + threadIdx.x;
    int r0 = blockIdx.y * rpc;
    float s = 0.f, q = 0.f;
#pragma unroll 4
    for (int r = 0; r < rpc; ++r) {
        float v = Z[(size_t)(r0 + r) * N + col];
        s += v; q += v * v;
    }
    psum[(size_t)blockIdx.y * N + col] = s;
    psq[(size_t)blockIdx.y * N + col] = q;
}

__global__ __launch_bounds__(256) void finstats_k(
    const float* __restrict__ psum, const float* __restrict__ psq,
    const float* __restrict__ g, const float* __restrict__ bt,
    float* __restrict__ a, float* __restrict__ c, int N, int chunks)
{
    int col = blockIdx.x * 256 + threadIdx.x;
    if (col >= N) return;
    float s = 0.f, q = 0.f;
    for (int ch = 0; ch < chunks; ++ch) {
        s += psum[(size_t)ch * N + col];
        q += psq[(size_t)ch * N + col];
    }
    const float inv = 1.0f / (float)B_ROWS;
    float mean = s * inv;
    float var = q * inv - mean * mean;
    float av = g[col] * rsqrtf(var + EPSV);
    a[col] = av;
    c[col] = bt[col] - mean * av;
}

// ---------------------------------------------------------------------------
// D1 = bf16(Z1*a + c), vectorized x4.
__global__ __launch_bounds__(256) void bn_apply_k(
    const float4* __restrict__ Z, const float* __restrict__ a,
    const float* __restrict__ c, ushort4* __restrict__ D,
    int total4, int nmask)
{
    int i = blockIdx.x * blockDim.x + threadIdx.x;
    int stride = gridDim.x * blockDim.x;
    for (; i < total4; i += stride) {
        float4 z = Z[i];
        int c0 = (i * 4) & nmask;
        float4 av = *(const float4*)(a + c0);
        float4 cv = *(const float4*)(c + c0);
        ushort4 o;
        o.x = f2bf(z.x * av.x + cv.x);
        o.y = f2bf(z.y * av.y + cv.y);
        o.z = f2bf(z.z * av.z + cv.z);
        o.w = f2bf(z.w * av.w + cv.w);
        D[i] = o;
    }
}

// ---------------------------------------------------------------------------
// out[b] = partial[b] + sum_c (Z2[b,c]*a2[c] + c2[c]); one wave per row.
__global__ __launch_bounds__(256) void final_k(
    const float* __restrict__ Z2, const float* __restrict__ a2,
    const float* __restrict__ c2, const float* __restrict__ partial,
    float* __restrict__ out)
{
    int w = threadIdx.x >> 6, lane = threadIdx.x & 63;
    int b = blockIdx.x * 4 + w;
    float4 z = *(const float4*)(Z2 + (size_t)b * H2 + lane * 4);
    float4 a = *(const float4*)(a2 + lane * 4);
    float4 c = *(const float4*)(c2 + lane * 4);
    float v = z.x * a.x + c.x + z.y * a.y + c.y + z.z * a.z + c.z + z.w * a.w + c.w;
#pragma unroll
    for (int m = 1; m < 64; m <<= 1) v += __shfl_xor(v, m);
    if (lane == 0) out[b] = partial[b] + v;
}

// ---------------------------------------------------------------------------
extern "C" void kernel_launch(void* const* d_in, const int* in_sizes, int n_in,
                              void* d_out, int out_size, void* d_ws, size_t ws_size,
                              hipStream_t stream)
{
    const int*   Xi   = (const int*)d_in[0];
    const float* Xv   = (const float*)d_in[1];
    const float* bias = (const float*)d_in[2];
    const float* dw1  = (const float*)d_in[3];
    const float* db1  = (const float*)d_in[4];
    const float* e1   = (const float*)d_in[5];
    const float* dw2  = (const float*)d_in[6];
    const float* db2  = (const float*)d_in[7];
    const float* e2   = (const float*)d_in[8];
    const float* W1   = (const float*)d_in[9];
    // d_in[10] = b1: cancels in BN (BN(x+const_col)==BN(x)) -> unused
    const float* g1   = (const float*)d_in[11];
    const float* bt1  = (const float*)d_in[12];
    const float* W2   = (const float*)d_in[13];
    // d_in[14] = b2: cancels in BN -> unused
    const float* g2   = (const float*)d_in[15];
    const float* bt2  = (const float*)d_in[16];

    char* ws = (char*)d_ws;
    size_t off = 0;
    auto alloc = [&](size_t bytes) { char* p = ws + off; off += (bytes + 255) & ~(size_t)255; return p; };

    u16*   so_bf  = (u16*)alloc((size_t)B_ROWS * D0 * 2);        // 21.0 MB
    float* Z2     = (float*)so_bf;                                // reuse: so dead after GEMM1, Z2 written after
    float* partial= (float*)alloc((size_t)B_ROWS * 4);
    u16*   W1T    = (u16*)alloc((size_t)H1 * D0 * 2);
    u16*   W2T    = (u16*)alloc((size_t)H2 * H1 * 2);
    float* psum   = (float*)alloc(65536 * 4);
    float* psq    = (float*)alloc(65536 * 4);
    float* a1     = (float*)alloc(H1 * 4);
    float* c1     = (float*)alloc(H1 * 4);
    float* a2     = (float*)alloc(H2 * 4);
    float* c2     = (float*)alloc(H2 * 4);
    float* Z1     = (float*)alloc((size_t)B_ROWS * H1 * 4);      // 33.6 MB
    u16*   D1     = (u16*)alloc((size_t)B_ROWS * H1 * 2);        // 16.8 MB
    (void)ws_size; (void)in_sizes; (void)n_in; (void)out_size;

    // 1) weights -> bf16 transposed
    transpose_bf16_k<<<dim3(D0 / 32, H1 / 32), 256, 0, stream>>>(W1, W1T, D0, H1);
    transpose_bf16_k<<<dim3(H1 / 32, H2 / 32), 256, 0, stream>>>(W2, W2T, H1, H2);
    // 2) embed + FM
    embed_k<<<B_ROWS / 16, 256, 0, stream>>>(Xi, Xv, bias, dw1, db1, e1, dw2, db2, e2,
                                             so_bf, partial);
    // 3) Z1 = so @ W1
    gemm_nt<<<dim3(B_ROWS / 128, H1 / 128), 256, 0, stream>>>(so_bf, W1T, Z1,
                                                              B_ROWS, H1, D0);
    // 4) BN1 stats
    colstats_k<<<dim3(H1 / 256, 128), 256, 0, stream>>>(Z1, psum, psq, H1, B_ROWS / 128);
    finstats_k<<<dim3((H1 + 255) / 256), 256, 0, stream>>>(psum, psq, g1, bt1, a1, c1, H1, 128);
    // 5) D1 = bf16(BN1(Z1))
    bn_apply_k<<<2048, 256, 0, stream>>>((const float4*)Z1, a1, c1, (ushort4*)D1,
                                         B_ROWS * H1 / 4, H1 - 1);
    // 6) Z2 = D1 @ W2
    gemm_nt<<<dim3(B_ROWS / 128, H2 / 128), 256, 0, stream>>>(D1, W2T, Z2,
                                                              B_ROWS, H2, H1);
    // 7) BN2 stats
    colstats_k<<<dim3(H2 / 256, 256), 256, 0, stream>>>(Z2, psum, psq, H2, B_ROWS / 256);
    finstats_k<<<dim3(1), 256, 0, stream>>>(psum, psq, g2, bt2, a2, c2, H2, 256);
    // 8) final: BN2 + row-sum + FM partial + bias
    final_k<<<B_ROWS / 4, 256, 0, stream>>>(Z2, a2, c2, partial, (float*)d_out);
}